// Round 1
// baseline (1002.884 us; speedup 1.0000x reference)
//
#include <hip/hip_runtime.h>
#include <hip/hip_bf16.h>
#include <stdint.h>

// Shapes (fixed by the problem)
#define BATCH 2048
#define I1DIM 256
#define NHID  512
#define KREAL 66049          // 257*257
#define KPAD  66112          // 64 * 1033
#define NSTEP 1033           // K-steps of 64
#define SPLITS 8
#define PERSPLIT 130         // ceil(1033/8)

typedef __attribute__((ext_vector_type(8))) short short8;
typedef __attribute__((ext_vector_type(4))) short short4v;
typedef __attribute__((ext_vector_type(4))) float f32x4;

#define AS1 __attribute__((address_space(1)))
#define AS3 __attribute__((address_space(3)))

__device__ __forceinline__ unsigned short f2bf(float f) {
    union { float f; unsigned int u; } v; v.f = f;
    unsigned int r = v.u + 0x7FFFu + ((v.u >> 16) & 1u);
    return (unsigned short)(r >> 16);
}

// ---------------------------------------------------------------------------
// Transpose + f32->bf16 convert: src[K][Nn] f32  ->  dst[Nn][Kpad] bf16.
// Rows k >= K are zero-padded. 64x64 tiles, 256 threads.
// ---------------------------------------------------------------------------
__global__ __launch_bounds__(256) void transpose_cvt(
        const float* __restrict__ src, unsigned short* __restrict__ dst,
        int K, int Nn, int Kpad) {
    __shared__ float T[64][65];
    int k0 = blockIdx.x * 64;
    int n0 = blockIdx.y * 64;
    int t  = threadIdx.x;
    int nn = t & 63, kk0 = t >> 6;
#pragma unroll
    for (int it = 0; it < 16; ++it) {
        int kk = it * 4 + kk0;
        int k  = k0 + kk;
        float v = 0.f;
        if (k < K) v = src[(long)k * Nn + n0 + nn];
        T[kk][nn] = v;
    }
    __syncthreads();
#pragma unroll
    for (int it = 0; it < 2; ++it) {
        int idx = it * 256 + t;
        int nl = idx >> 3, ch = idx & 7;
        short8 o;
#pragma unroll
        for (int e = 0; e < 8; ++e) o[e] = (short)f2bf(T[ch * 8 + e][nl]);
        *reinterpret_cast<short8*>(&dst[(long)(n0 + nl) * Kpad + k0 + ch * 8]) = o;
    }
}

// ---------------------------------------------------------------------------
// Stage a [128 rows][64 k] bf16 tile from row-major global (ld elems) into
// LDS via global_load_lds (16B), with XOR swizzle applied by permuting the
// per-lane *source* chunk (LDS dest must stay linear).
// LDS slot (row, s) holds global chunk (s ^ (row&7)).  256 threads.
// ---------------------------------------------------------------------------
__device__ __forceinline__ void stage_tile128(const unsigned short* __restrict__ g,
        long row0, long k0, long ld, unsigned short* lds) {
    int t = threadIdx.x;
    int wave = t >> 6, lane = t & 63;
    int rl = lane >> 3;               // 0..7 row within 8-row group
    int ch = (lane & 7) ^ rl;         // swizzled source chunk
    const unsigned short* src0 = g + (row0 + wave * 8 + rl) * ld + k0 + ch * 8;
#pragma unroll
    for (int r = 0; r < 4; ++r) {
        const unsigned short* src = src0 + (long)r * 32 * ld;
        unsigned short* dst = lds + (r * 32 + wave * 8) * 64;   // wave-uniform
        __builtin_amdgcn_global_load_lds((const AS1 unsigned int*)src,
                                         (AS3 unsigned int*)dst, 16, 0, 0);
    }
}

// ---------------------------------------------------------------------------
// Generate the fusion A-tile [128 rows][64 k] bf16 directly into LDS (same
// swizzled layout as stage_tile128).  fusion[m][k] = a(m, k/257) * c(m, k%257)
// with a(m,i)=inp1[m][i] (i<256), 1 (i==256), 0 (pad); c similarly.
// ---------------------------------------------------------------------------
__device__ __forceinline__ void stage_A_gen(const float* __restrict__ inp1,
        const float* __restrict__ inp2, int m0, int kbase, unsigned short* lds) {
    int t = threadIdx.x;
    int rl = t >> 3;            // 0..31
    int kslot = t & 7;          // 16B chunk within row
#pragma unroll
    for (int r = 0; r < 4; ++r) {
        int rowl = r * 32 + rl;
        int m = m0 + rowl;
        int kg = kbase + kslot * 8;
        int i = kg / 257;
        int j = kg - i * 257;
        float a0 = (i < 256) ? inp1[m * 256 + i] : (i == 256 ? 1.0f : 0.0f);
        int i1 = i + 1;
        float a1 = (i1 < 256) ? inp1[m * 256 + i1] : (i1 == 256 ? 1.0f : 0.0f);
        short8 o;
        int jj = j;
        float a = a0;
#pragma unroll
        for (int e = 0; e < 8; ++e) {
            float c = (jj < 256) ? inp2[m * 256 + jj] : 1.0f;
            o[e] = (short)f2bf(a * c);
            ++jj;
            if (jj == 257) { jj = 0; a = a1; }
        }
        int swch = kslot ^ (rowl & 7);
        *reinterpret_cast<short8*>(&lds[rowl * 64 + swch * 8]) = o;
    }
}

// Fragment read: logical (rowbase+(lane&15), k = kofs + (lane>>4)*8 .. +8)
__device__ __forceinline__ short8 read_frag(const unsigned short* lds,
        int rowbase, int kofs, int lane) {
    int row = rowbase + (lane & 15);
    int chunkL = (kofs >> 3) + (lane >> 4);
    int sw = chunkL ^ (row & 7);
    return *reinterpret_cast<const short8*>(&lds[row * 64 + sw * 8]);
}

// ---------------------------------------------------------------------------
// GEMM1: hacc += fusion[128-tile] @ W1t^T[128-tile], split-K via atomics.
// grid = 16(M) * 4(N) * SPLITS, 256 threads (4 waves, 2x2), BK=64.
// ---------------------------------------------------------------------------
__global__ __launch_bounds__(256) void gemm1_kernel(
        const float* __restrict__ inp1, const float* __restrict__ inp2,
        const unsigned short* __restrict__ W1t, float* __restrict__ hacc) {
    __shared__ unsigned short A_s[128 * 64];
    __shared__ unsigned short B_s[128 * 64];
    int bid = blockIdx.x;
    int s   = bid >> 6;
    int rem = bid & 63;
    int m0 = (rem >> 2) * 128;
    int n0 = (rem & 3) * 128;
    int st0 = s * PERSPLIT;
    int st1 = st0 + PERSPLIT; if (st1 > NSTEP) st1 = NSTEP;

    int lane = threadIdx.x & 63;
    int wv = threadIdx.x >> 6;
    int wm = (wv >> 1) * 64;
    int wn = (wv & 1) * 64;

    f32x4 acc[4][4];
#pragma unroll
    for (int a = 0; a < 4; ++a)
#pragma unroll
        for (int b = 0; b < 4; ++b) acc[a][b] = (f32x4){0.f, 0.f, 0.f, 0.f};

    for (int st = st0; st < st1; ++st) {
        int kbase = st * 64;
        __syncthreads();
        stage_tile128(W1t, n0, kbase, KPAD, B_s);
        stage_A_gen(inp1, inp2, m0, kbase, A_s);
        __syncthreads();
#pragma unroll
        for (int kk = 0; kk < 2; ++kk) {
            short8 aF[4], bF[4];
#pragma unroll
            for (int fm = 0; fm < 4; ++fm) aF[fm] = read_frag(A_s, wm + fm * 16, kk * 32, lane);
#pragma unroll
            for (int fn = 0; fn < 4; ++fn) bF[fn] = read_frag(B_s, wn + fn * 16, kk * 32, lane);
#pragma unroll
            for (int fm = 0; fm < 4; ++fm)
#pragma unroll
                for (int fn = 0; fn < 4; ++fn)
                    acc[fm][fn] = __builtin_amdgcn_mfma_f32_16x16x32_bf16(
                        aF[fm], bF[fn], acc[fm][fn], 0, 0, 0);
        }
    }
    // epilogue: atomic split-K accumulate into f32 hacc (= d_out scratch)
    int cl = lane & 15;
    int r4 = (lane >> 4) * 4;
#pragma unroll
    for (int fm = 0; fm < 4; ++fm)
#pragma unroll
        for (int fn = 0; fn < 4; ++fn)
#pragma unroll
            for (int r = 0; r < 4; ++r) {
                int row = m0 + wm + fm * 16 + r4 + r;
                int col = n0 + wn + fn * 16 + cl;
                atomicAdd(&hacc[row * NHID + col], acc[fm][fn][r]);
            }
}

// h = bf16(relu(hacc + b1))
__global__ __launch_bounds__(256) void bias_relu_h_kernel(
        const float* __restrict__ hacc, const float* __restrict__ b1,
        unsigned short* __restrict__ h) {
    int idx = blockIdx.x * 256 + threadIdx.x;   // 262144 total, 4 elems each
    f32x4 v = ((const f32x4*)hacc)[idx];
    int col = (idx & 127) << 2;
    f32x4 bb = *(const f32x4*)(b1 + col);
    short4v o;
#pragma unroll
    for (int e = 0; e < 4; ++e) {
        float x = v[e] + bb[e];
        x = fmaxf(x, 0.f);
        o[e] = (short)f2bf(x);
    }
    ((short4v*)h)[idx] = o;
}

// ---------------------------------------------------------------------------
// GEMM2: out = relu(h @ W2 + b2).  M=2048,N=512,K=512.  grid 16x4.
// ---------------------------------------------------------------------------
__global__ __launch_bounds__(256) void gemm2_kernel(
        const unsigned short* __restrict__ h, const unsigned short* __restrict__ W2t,
        const float* __restrict__ b2, float* __restrict__ out) {
    __shared__ unsigned short A_s[128 * 64];
    __shared__ unsigned short B_s[128 * 64];
    int m0 = (blockIdx.x >> 2) * 128;
    int n0 = (blockIdx.x & 3) * 128;
    int lane = threadIdx.x & 63;
    int wv = threadIdx.x >> 6;
    int wm = (wv >> 1) * 64;
    int wn = (wv & 1) * 64;

    f32x4 acc[4][4];
#pragma unroll
    for (int a = 0; a < 4; ++a)
#pragma unroll
        for (int b = 0; b < 4; ++b) acc[a][b] = (f32x4){0.f, 0.f, 0.f, 0.f};

    for (int st = 0; st < 8; ++st) {
        int kbase = st * 64;
        __syncthreads();
        stage_tile128(h,   m0, kbase, NHID, A_s);
        stage_tile128(W2t, n0, kbase, NHID, B_s);
        __syncthreads();
#pragma unroll
        for (int kk = 0; kk < 2; ++kk) {
            short8 aF[4], bF[4];
#pragma unroll
            for (int fm = 0; fm < 4; ++fm) aF[fm] = read_frag(A_s, wm + fm * 16, kk * 32, lane);
#pragma unroll
            for (int fn = 0; fn < 4; ++fn) bF[fn] = read_frag(B_s, wn + fn * 16, kk * 32, lane);
#pragma unroll
            for (int fm = 0; fm < 4; ++fm)
#pragma unroll
                for (int fn = 0; fn < 4; ++fn)
                    acc[fm][fn] = __builtin_amdgcn_mfma_f32_16x16x32_bf16(
                        aF[fm], bF[fn], acc[fm][fn], 0, 0, 0);
        }
    }
    int cl = lane & 15;
    int r4 = (lane >> 4) * 4;
#pragma unroll
    for (int fm = 0; fm < 4; ++fm)
#pragma unroll
        for (int fn = 0; fn < 4; ++fn)
#pragma unroll
            for (int r = 0; r < 4; ++r) {
                int row = m0 + wm + fm * 16 + r4 + r;
                int col = n0 + wn + fn * 16 + cl;
                float x = acc[fm][fn][r] + b2[col];
                out[row * NHID + col] = fmaxf(x, 0.f);
            }
}

extern "C" void kernel_launch(void* const* d_in, const int* in_sizes, int n_in,
                              void* d_out, int out_size, void* d_ws, size_t ws_size,
                              hipStream_t stream) {
    const float* inp1 = (const float*)d_in[0];
    const float* inp2 = (const float*)d_in[1];
    const float* W1   = (const float*)d_in[2];
    const float* b1   = (const float*)d_in[3];
    const float* W2   = (const float*)d_in[4];
    const float* b2   = (const float*)d_in[5];
    float* out = (float*)d_out;

    // workspace layout (ws needs ~70.5 MB)
    size_t off = 0;
    auto alloc = [&](size_t bytes) {
        void* p = (char*)d_ws + off;
        off += (bytes + 255) & ~(size_t)255;
        return p;
    };
    unsigned short* W1t = (unsigned short*)alloc((size_t)NHID * KPAD * 2);
    unsigned short* W2t = (unsigned short*)alloc((size_t)NHID * NHID * 2);
    unsigned short* h   = (unsigned short*)alloc((size_t)BATCH * NHID * 2);
    (void)ws_size; (void)in_sizes; (void)n_in; (void)out_size;

    // d_out doubles as the f32 split-K accumulator for h_pre
    hipMemsetAsync(d_out, 0, (size_t)BATCH * NHID * 4, stream);

    transpose_cvt<<<dim3(KPAD / 64, NHID / 64), 256, 0, stream>>>(W1, W1t, KREAL, NHID, KPAD);
    transpose_cvt<<<dim3(NHID / 64, NHID / 64), 256, 0, stream>>>(W2, W2t, NHID, NHID, NHID);

    gemm1_kernel<<<64 * SPLITS, 256, 0, stream>>>(inp1, inp2, W1t, (float*)d_out);
    bias_relu_h_kernel<<<(BATCH * NHID / 4) / 256, 256, 0, stream>>>((const float*)d_out, b1, h);
    gemm2_kernel<<<64, 256, 0, stream>>>(h, W2t, b2, out);
}

// Round 2
// 539.884 us; speedup vs baseline: 1.8576x; 1.8576x over previous
//
#include <hip/hip_runtime.h>
#include <hip/hip_bf16.h>
#include <stdint.h>

// Shapes (fixed by the problem)
#define BATCH 2048
#define I1DIM 256
#define NHID  512
#define KREAL 66049          // 257*257
#define KPAD  66112          // 64 * 1033
#define NSTEP 1033           // K-steps of 64
#define SPLITS 16
#define PERSPLIT 65          // ceil(1033/16)

typedef __attribute__((ext_vector_type(8))) short short8;
typedef __attribute__((ext_vector_type(4))) short short4v;
typedef __attribute__((ext_vector_type(4))) float f32x4;

#define AS1 __attribute__((address_space(1)))
#define AS3 __attribute__((address_space(3)))

__device__ __forceinline__ unsigned short f2bf(float f) {
    union { float f; unsigned int u; } v; v.f = f;
    unsigned int r = v.u + 0x7FFFu + ((v.u >> 16) & 1u);
    return (unsigned short)(r >> 16);
}

// ---------------------------------------------------------------------------
// Transpose + f32->bf16 convert: src[K][Nn] f32  ->  dst[Nn][Kpad] bf16.
// Rows k >= K are zero-padded. 64x64 tiles, 256 threads.
// ---------------------------------------------------------------------------
__global__ __launch_bounds__(256) void transpose_cvt(
        const float* __restrict__ src, unsigned short* __restrict__ dst,
        int K, int Nn, int Kpad) {
    __shared__ float T[64][65];
    int k0 = blockIdx.x * 64;
    int n0 = blockIdx.y * 64;
    int t  = threadIdx.x;
    int nn = t & 63, kk0 = t >> 6;
#pragma unroll
    for (int it = 0; it < 16; ++it) {
        int kk = it * 4 + kk0;
        int k  = k0 + kk;
        float v = 0.f;
        if (k < K) v = src[(long)k * Nn + n0 + nn];
        T[kk][nn] = v;
    }
    __syncthreads();
#pragma unroll
    for (int it = 0; it < 2; ++it) {
        int idx = it * 256 + t;
        int nl = idx >> 3, ch = idx & 7;
        short8 o;
#pragma unroll
        for (int e = 0; e < 8; ++e) o[e] = (short)f2bf(T[ch * 8 + e][nl]);
        *reinterpret_cast<short8*>(&dst[(long)(n0 + nl) * Kpad + k0 + ch * 8]) = o;
    }
}

// ---------------------------------------------------------------------------
// Materialize fusion matrix F[b][k] = a(b, k/257) * c(b, k%257), bf16,
// k in [0, KPAD); zeros for k >= KREAL (emerge from a(i>=257)=0).
// One block per batch row; 16B coalesced writes; inp rows are L1-resident.
// ---------------------------------------------------------------------------
__global__ __launch_bounds__(256) void fusion_gen(
        const float* __restrict__ inp1, const float* __restrict__ inp2,
        unsigned short* __restrict__ F) {
    int b = blockIdx.x;
    const float* a_row = inp1 + b * 256;
    const float* c_row = inp2 + b * 256;
    unsigned short* frow = F + (long)b * KPAD;
    for (int ch = threadIdx.x; ch < KPAD / 8; ch += 256) {
        int kg = ch * 8;
        int i = kg / 257;               // magic-mul division (compile-time const)
        int j = kg - i * 257;
        float a0 = (i < 256) ? a_row[i] : (i == 256 ? 1.0f : 0.0f);
        int i1 = i + 1;
        float a1 = (i1 < 256) ? a_row[i1] : (i1 == 256 ? 1.0f : 0.0f);
        short8 o;
#pragma unroll
        for (int e = 0; e < 8; ++e) {
            int jj = j + e;
            int jm = (jj < 257) ? jj : jj - 257;    // wrap to next i-row
            float a = (jj < 257) ? a0 : a1;
            int idx = (jm < 256) ? jm : 0;          // keep load in-bounds
            float cv = (jm < 256) ? c_row[idx] : 1.0f;
            o[e] = (short)f2bf(a * cv);
        }
        *reinterpret_cast<short8*>(&frow[kg]) = o;
    }
}

// ---------------------------------------------------------------------------
// Stage a [128 rows][64 k] bf16 tile from row-major global (ld elems) into
// LDS via global_load_lds (16B), with XOR swizzle applied by permuting the
// per-lane *source* chunk (LDS dest must stay linear).
// LDS slot (row, s) holds global chunk (s ^ (row&7)).  256 threads.
// ---------------------------------------------------------------------------
__device__ __forceinline__ void stage_tile128(const unsigned short* __restrict__ g,
        long row0, long k0, long ld, unsigned short* lds) {
    int t = threadIdx.x;
    int wave = t >> 6, lane = t & 63;
    int rl = lane >> 3;               // 0..7 row within 8-row group
    int ch = (lane & 7) ^ rl;         // swizzled source chunk
    const unsigned short* src0 = g + (row0 + wave * 8 + rl) * ld + k0 + ch * 8;
#pragma unroll
    for (int r = 0; r < 4; ++r) {
        const unsigned short* src = src0 + (long)r * 32 * ld;
        unsigned short* dst = lds + (r * 32 + wave * 8) * 64;   // wave-uniform
        __builtin_amdgcn_global_load_lds((const AS1 unsigned int*)src,
                                         (AS3 unsigned int*)dst, 16, 0, 0);
    }
}

// Fragment read: logical (rowbase+(lane&15), k = kofs + (lane>>4)*8 .. +8)
__device__ __forceinline__ short8 read_frag(const unsigned short* lds,
        int rowbase, int kofs, int lane) {
    int row = rowbase + (lane & 15);
    int chunkL = (kofs >> 3) + (lane >> 4);
    int sw = chunkL ^ (row & 7);
    return *reinterpret_cast<const short8*>(&lds[row * 64 + sw * 8]);
}

// ---------------------------------------------------------------------------
// GEMM1: hacc += F[128-tile] @ W1t^T[128-tile], split-K via atomics.
// grid = 16(M) * 4(N) * SPLITS = 1024 blocks, 256 threads (4 waves, 2x2).
// XCD swizzle: logical id has m fastest so the 16 m-blocks sharing a W1t
// slice (and 4 n-blocks sharing an F slice) stay on one XCD's L2.
// ---------------------------------------------------------------------------
__global__ __launch_bounds__(256) void gemm1_kernel(
        const unsigned short* __restrict__ F, const unsigned short* __restrict__ W1t,
        float* __restrict__ hacc) {
    __shared__ unsigned short A_s[128 * 64];
    __shared__ unsigned short B_s[128 * 64];
    // T1: nwg = 1024 divisible by 8 -> simple bijective swizzle
    int bid = (blockIdx.x & 7) * 128 + (blockIdx.x >> 3);
    int m0 = (bid & 15) * 128;
    int n0 = ((bid >> 4) & 3) * 128;
    int s  = bid >> 6;
    int st0 = s * PERSPLIT;
    int st1 = st0 + PERSPLIT; if (st1 > NSTEP) st1 = NSTEP;

    int lane = threadIdx.x & 63;
    int wv = threadIdx.x >> 6;
    int wm = (wv >> 1) * 64;
    int wn = (wv & 1) * 64;

    f32x4 acc[4][4];
#pragma unroll
    for (int a = 0; a < 4; ++a)
#pragma unroll
        for (int b = 0; b < 4; ++b) acc[a][b] = (f32x4){0.f, 0.f, 0.f, 0.f};

    for (int st = st0; st < st1; ++st) {
        int kbase = st * 64;
        __syncthreads();
        stage_tile128(F,   m0, kbase, KPAD, A_s);
        stage_tile128(W1t, n0, kbase, KPAD, B_s);
        __syncthreads();
#pragma unroll
        for (int kk = 0; kk < 2; ++kk) {
            short8 aF[4], bF[4];
#pragma unroll
            for (int fm = 0; fm < 4; ++fm) aF[fm] = read_frag(A_s, wm + fm * 16, kk * 32, lane);
#pragma unroll
            for (int fn = 0; fn < 4; ++fn) bF[fn] = read_frag(B_s, wn + fn * 16, kk * 32, lane);
#pragma unroll
            for (int fm = 0; fm < 4; ++fm)
#pragma unroll
                for (int fn = 0; fn < 4; ++fn)
                    acc[fm][fn] = __builtin_amdgcn_mfma_f32_16x16x32_bf16(
                        aF[fm], bF[fn], acc[fm][fn], 0, 0, 0);
        }
    }
    // epilogue: atomic split-K accumulate into f32 hacc (= d_out scratch)
    int cl = lane & 15;
    int r4 = (lane >> 4) * 4;
#pragma unroll
    for (int fm = 0; fm < 4; ++fm)
#pragma unroll
        for (int fn = 0; fn < 4; ++fn)
#pragma unroll
            for (int r = 0; r < 4; ++r) {
                int row = m0 + wm + fm * 16 + r4 + r;
                int col = n0 + wn + fn * 16 + cl;
                atomicAdd(&hacc[row * NHID + col], acc[fm][fn][r]);
            }
}

// h = bf16(relu(hacc + b1))
__global__ __launch_bounds__(256) void bias_relu_h_kernel(
        const float* __restrict__ hacc, const float* __restrict__ b1,
        unsigned short* __restrict__ h) {
    int idx = blockIdx.x * 256 + threadIdx.x;   // 262144 total, 4 elems each
    f32x4 v = ((const f32x4*)hacc)[idx];
    int col = (idx & 127) << 2;
    f32x4 bb = *(const f32x4*)(b1 + col);
    short4v o;
#pragma unroll
    for (int e = 0; e < 4; ++e) {
        float x = v[e] + bb[e];
        x = fmaxf(x, 0.f);
        o[e] = (short)f2bf(x);
    }
    ((short4v*)h)[idx] = o;
}

// ---------------------------------------------------------------------------
// GEMM2: out = relu(h @ W2 + b2).  M=2048,N=512,K=512.  grid 16x4.
// ---------------------------------------------------------------------------
__global__ __launch_bounds__(256) void gemm2_kernel(
        const unsigned short* __restrict__ h, const unsigned short* __restrict__ W2t,
        const float* __restrict__ b2, float* __restrict__ out) {
    __shared__ unsigned short A_s[128 * 64];
    __shared__ unsigned short B_s[128 * 64];
    int m0 = (blockIdx.x >> 2) * 128;
    int n0 = (blockIdx.x & 3) * 128;
    int lane = threadIdx.x & 63;
    int wv = threadIdx.x >> 6;
    int wm = (wv >> 1) * 64;
    int wn = (wv & 1) * 64;

    f32x4 acc[4][4];
#pragma unroll
    for (int a = 0; a < 4; ++a)
#pragma unroll
        for (int b = 0; b < 4; ++b) acc[a][b] = (f32x4){0.f, 0.f, 0.f, 0.f};

    for (int st = 0; st < 8; ++st) {
        int kbase = st * 64;
        __syncthreads();
        stage_tile128(h,   m0, kbase, NHID, A_s);
        stage_tile128(W2t, n0, kbase, NHID, B_s);
        __syncthreads();
#pragma unroll
        for (int kk = 0; kk < 2; ++kk) {
            short8 aF[4], bF[4];
#pragma unroll
            for (int fm = 0; fm < 4; ++fm) aF[fm] = read_frag(A_s, wm + fm * 16, kk * 32, lane);
#pragma unroll
            for (int fn = 0; fn < 4; ++fn) bF[fn] = read_frag(B_s, wn + fn * 16, kk * 32, lane);
#pragma unroll
            for (int fm = 0; fm < 4; ++fm)
#pragma unroll
                for (int fn = 0; fn < 4; ++fn)
                    acc[fm][fn] = __builtin_amdgcn_mfma_f32_16x16x32_bf16(
                        aF[fm], bF[fn], acc[fm][fn], 0, 0, 0);
        }
    }
    int cl = lane & 15;
    int r4 = (lane >> 4) * 4;
#pragma unroll
    for (int fm = 0; fm < 4; ++fm)
#pragma unroll
        for (int fn = 0; fn < 4; ++fn)
#pragma unroll
            for (int r = 0; r < 4; ++r) {
                int row = m0 + wm + fm * 16 + r4 + r;
                int col = n0 + wn + fn * 16 + cl;
                float x = acc[fm][fn][r] + b2[col];
                out[row * NHID + col] = fmaxf(x, 0.f);
            }
}

extern "C" void kernel_launch(void* const* d_in, const int* in_sizes, int n_in,
                              void* d_out, int out_size, void* d_ws, size_t ws_size,
                              hipStream_t stream) {
    const float* inp1 = (const float*)d_in[0];
    const float* inp2 = (const float*)d_in[1];
    const float* W1   = (const float*)d_in[2];
    const float* b1   = (const float*)d_in[3];
    const float* W2   = (const float*)d_in[4];
    const float* b2   = (const float*)d_in[5];
    float* out = (float*)d_out;

    // workspace layout (~341 MB)
    size_t off = 0;
    auto alloc = [&](size_t bytes) {
        void* p = (char*)d_ws + off;
        off += (bytes + 255) & ~(size_t)255;
        return p;
    };
    unsigned short* W1t = (unsigned short*)alloc((size_t)NHID * KPAD * 2);
    unsigned short* W2t = (unsigned short*)alloc((size_t)NHID * NHID * 2);
    unsigned short* h   = (unsigned short*)alloc((size_t)BATCH * NHID * 2);
    unsigned short* Fm  = (unsigned short*)alloc((size_t)BATCH * KPAD * 2);
    (void)ws_size; (void)in_sizes; (void)n_in; (void)out_size;

    // d_out doubles as the f32 split-K accumulator for h_pre
    hipMemsetAsync(d_out, 0, (size_t)BATCH * NHID * 4, stream);

    fusion_gen<<<BATCH, 256, 0, stream>>>(inp1, inp2, Fm);
    transpose_cvt<<<dim3(KPAD / 64, NHID / 64), 256, 0, stream>>>(W1, W1t, KREAL, NHID, KPAD);
    transpose_cvt<<<dim3(NHID / 64, NHID / 64), 256, 0, stream>>>(W2, W2t, NHID, NHID, NHID);

    gemm1_kernel<<<64 * SPLITS, 256, 0, stream>>>(Fm, W1t, (float*)d_out);
    bias_relu_h_kernel<<<(BATCH * NHID / 4) / 256, 256, 0, stream>>>((const float*)d_out, b1, h);
    gemm2_kernel<<<64, 256, 0, stream>>>(h, W2t, b2, out);
}

// Round 3
// 274.364 us; speedup vs baseline: 3.6553x; 1.9678x over previous
//
#include <hip/hip_runtime.h>
#include <stdint.h>

// Shapes (fixed by the problem)
#define BATCH 2048
#define NHID  512
#define KMAIN 65792          // 257*256 = 1028*64  (k = i*256 + j, j<256)
#define KPAD  66112          // KMAIN + 320 = 1033*64 (tail: k-KMAIN = i, j=256 col)
#define NSTEP 1033
#define TAILSTEP 1028        // KMAIN/64
#define SPLITS 16
#define PERSPLIT 65          // ceil(1033/16)
#define AW 320               // a_tab row width (256 vals, 1.0 at 256, zeros to 320)
#define CW 256               // c_tab row width

typedef __attribute__((ext_vector_type(8))) short short8;
typedef __attribute__((ext_vector_type(4))) short short4v;
typedef __attribute__((ext_vector_type(4))) float f32x4;

#define AS1 __attribute__((address_space(1)))
#define AS3 __attribute__((address_space(3)))

__device__ __forceinline__ unsigned short f2bf(float f) {
    union { float f; unsigned int u; } v; v.f = f;
    unsigned int r = v.u + 0x7FFFu + ((v.u >> 16) & 1u);
    return (unsigned short)(r >> 16);
}
__device__ __forceinline__ float bf2f(unsigned short u) {
    union { unsigned int i; float f; } v; v.i = ((unsigned int)u) << 16;
    return v.f;
}

// W1 source row for permuted k (or -1 for zero-pad)
__device__ __forceinline__ int w1_src_row(int k) {
    if (k < KMAIN) return (k >> 8) * 257 + (k & 255);   // i*257 + j
    int i = k - KMAIN;
    return (i < 257) ? (i * 257 + 256) : -1;             // (i, j=256) column
}

// ---------------------------------------------------------------------------
// Merged prep: W1t (permuted transpose+cvt), W2t (transpose+cvt),
// a_tab [2048][320] bf16, c_tab [2048][256] bf16.  One launch.
// grid = 8264 (W1 tiles) + 64 (W2 tiles) + 64 (tab builders)
// ---------------------------------------------------------------------------
__global__ __launch_bounds__(256) void prep_kernel(
        const float* __restrict__ inp1, const float* __restrict__ inp2,
        const float* __restrict__ W1, const float* __restrict__ W2,
        unsigned short* __restrict__ W1t, unsigned short* __restrict__ W2t,
        unsigned short* __restrict__ a_tab, unsigned short* __restrict__ c_tab) {
    __shared__ float T[64][65];
    int b = blockIdx.x;
    int t = threadIdx.x;

    if (b < 8264 + 64) {
        // ---- transpose+cvt a 64k x 64n tile ----
        const float* src; unsigned short* dst; int k0, n0, Kpad; bool perm;
        if (b < 8264) {
            int kt = b % 1033, nt = b / 1033;
            src = W1; dst = W1t; k0 = kt * 64; n0 = nt * 64; Kpad = KPAD; perm = true;
        } else {
            int bb = b - 8264;
            int kt = bb & 7, nt = bb >> 3;
            src = W2; dst = W2t; k0 = kt * 64; n0 = nt * 64; Kpad = 512; perm = false;
        }
        int nn = t & 63, kk0 = t >> 6;
#pragma unroll
        for (int it = 0; it < 16; ++it) {
            int kk = it * 4 + kk0;
            int k = k0 + kk;
            int row = perm ? w1_src_row(k) : k;
            float v = (row >= 0) ? src[(long)row * NHID + n0 + nn] : 0.f;
            T[kk][nn] = v;
        }
        __syncthreads();
#pragma unroll
        for (int it = 0; it < 2; ++it) {
            int idx = it * 256 + t;
            int nl = idx >> 3, ch = idx & 7;
            short8 o;
#pragma unroll
            for (int e = 0; e < 8; ++e) o[e] = (short)f2bf(T[ch * 8 + e][nl]);
            *reinterpret_cast<short8*>(&dst[(long)(n0 + nl) * Kpad + k0 + ch * 8]) = o;
        }
    } else {
        // ---- a_tab / c_tab builder: 32 batch rows per block ----
        int r0 = (b - 8328) * 32;
        for (int idx = t; idx < 32 * (AW / 8); idx += 256) {   // a_tab: 40 chunks/row
            int r = idx / 40, ch = idx - r * 40;
            int m = r0 + r;
            short8 o;
#pragma unroll
            for (int e = 0; e < 8; ++e) {
                int i = ch * 8 + e;
                float v = (i < 256) ? inp1[m * 256 + i] : (i == 256 ? 1.0f : 0.0f);
                o[e] = (short)f2bf(v);
            }
            *reinterpret_cast<short8*>(&a_tab[m * AW + ch * 8]) = o;
        }
        for (int idx = t; idx < 32 * (CW / 8); idx += 256) {   // c_tab: 32 chunks/row
            int r = idx >> 5, ch = idx & 31;
            int m = r0 + r;
            short8 o;
#pragma unroll
            for (int e = 0; e < 8; ++e) o[e] = (short)f2bf(inp2[m * 256 + ch * 8 + e]);
            *reinterpret_cast<short8*>(&c_tab[m * CW + ch * 8]) = o;
        }
    }
}

// ---------------------------------------------------------------------------
// Stage a [128 rows][64 k] bf16 tile from row-major global into LDS via
// global_load_lds (16B), XOR swizzle via permuted per-lane source chunk.
// LDS slot (row, s) holds global chunk (s ^ (row&7)).  256 threads.
// ---------------------------------------------------------------------------
__device__ __forceinline__ void stage_tile128(const unsigned short* __restrict__ g,
        long row0, long k0, long ld, unsigned short* lds) {
    int t = threadIdx.x;
    int wave = t >> 6, lane = t & 63;
    int rl = lane >> 3;
    int ch = (lane & 7) ^ rl;
    const unsigned short* src0 = g + (row0 + wave * 8 + rl) * ld + k0 + ch * 8;
#pragma unroll
    for (int r = 0; r < 4; ++r) {
        const unsigned short* src = src0 + (long)r * 32 * ld;
        unsigned short* dst = lds + (r * 32 + wave * 8) * 64;   // wave-uniform
        __builtin_amdgcn_global_load_lds((const AS1 unsigned int*)src,
                                         (AS3 unsigned int*)dst, 16, 0, 0);
    }
}

// ---------------------------------------------------------------------------
// Generate the A-tile [128 rows][64 k] in-register from a_tab/c_tab and
// ds_write it in the same swizzled layout.  Main region only (k < KMAIN):
// i = kbase>>8 is uniform, j chunks are 16B-aligned, branch-free.
// ---------------------------------------------------------------------------
__device__ __forceinline__ void stage_A_gen(
        const unsigned short* __restrict__ a_tab,
        const unsigned short* __restrict__ c_tab,
        int m0, int kbase, unsigned short* lds) {
    int t = threadIdx.x;
    int rl = t >> 3;                       // 0..31
    int kslot = t & 7;
    int i = kbase >> 8;                    // uniform over the tile
    int j0 = (kbase & 255) + kslot * 8;    // per-lane, 16B aligned, <= 248
#pragma unroll
    for (int r = 0; r < 4; ++r) {
        int rowl = r * 32 + rl;
        int m = m0 + rowl;
        float av = bf2f(a_tab[m * AW + i]);
        short8 c8 = *reinterpret_cast<const short8*>(&c_tab[m * CW + j0]);
        short8 o;
#pragma unroll
        for (int e = 0; e < 8; ++e) o[e] = (short)f2bf(av * bf2f((unsigned short)c8[e]));
        int swch = kslot ^ (rowl & 7);
        *reinterpret_cast<short8*>(&lds[rowl * 64 + swch * 8]) = o;
    }
}

// Fragment read: logical (rowbase+(lane&15), k = kofs + (lane>>4)*8 .. +8)
__device__ __forceinline__ short8 read_frag(const unsigned short* lds,
        int rowbase, int kofs, int lane) {
    int row = rowbase + (lane & 15);
    int chunkL = (kofs >> 3) + (lane >> 4);
    int sw = chunkL ^ (row & 7);
    return *reinterpret_cast<const short8*>(&lds[row * 64 + sw * 8]);
}

// ---------------------------------------------------------------------------
// GEMM1: hacc += A(m-tile) @ W1t^T(n-tile), split-K via atomics.
// A generated on the fly (main) or loaded from a_tab (tail).
// grid = 16(M) * 4(N) * SPLITS = 1024 blocks, 256 threads (4 waves, 2x2).
// ---------------------------------------------------------------------------
__global__ __launch_bounds__(256) void gemm1_kernel(
        const unsigned short* __restrict__ a_tab,
        const unsigned short* __restrict__ c_tab,
        const unsigned short* __restrict__ W1t, float* __restrict__ hacc) {
    __shared__ unsigned short A_s[128 * 64];
    __shared__ unsigned short B_s[128 * 64];
    // T1: nwg = 1024 divisible by 8 -> bijective XCD swizzle, m fastest
    int bid = (blockIdx.x & 7) * 128 + (blockIdx.x >> 3);
    int m0 = (bid & 15) * 128;
    int n0 = ((bid >> 4) & 3) * 128;
    int s  = bid >> 6;
    int st0 = s * PERSPLIT;
    int st1 = st0 + PERSPLIT; if (st1 > NSTEP) st1 = NSTEP;

    int lane = threadIdx.x & 63;
    int wv = threadIdx.x >> 6;
    int wm = (wv >> 1) * 64;
    int wn = (wv & 1) * 64;

    f32x4 acc[4][4];
#pragma unroll
    for (int a = 0; a < 4; ++a)
#pragma unroll
        for (int b = 0; b < 4; ++b) acc[a][b] = (f32x4){0.f, 0.f, 0.f, 0.f};

    for (int st = st0; st < st1; ++st) {
        int kbase = st * 64;
        __syncthreads();
        stage_tile128(W1t, n0, kbase, KPAD, B_s);   // async loads in flight...
        if (st < TAILSTEP)
            stage_A_gen(a_tab, c_tab, m0, kbase, A_s);   // ...VALU gen overlaps
        else
            stage_tile128(a_tab, m0, kbase - KMAIN, AW, A_s);
        __syncthreads();
#pragma unroll
        for (int kk = 0; kk < 2; ++kk) {
            short8 aF[4], bF[4];
#pragma unroll
            for (int fm = 0; fm < 4; ++fm) aF[fm] = read_frag(A_s, wm + fm * 16, kk * 32, lane);
#pragma unroll
            for (int fn = 0; fn < 4; ++fn) bF[fn] = read_frag(B_s, wn + fn * 16, kk * 32, lane);
#pragma unroll
            for (int fm = 0; fm < 4; ++fm)
#pragma unroll
                for (int fn = 0; fn < 4; ++fn)
                    acc[fm][fn] = __builtin_amdgcn_mfma_f32_16x16x32_bf16(
                        aF[fm], bF[fn], acc[fm][fn], 0, 0, 0);
        }
    }
    // epilogue: atomic split-K accumulate into f32 hacc (= d_out scratch)
    int cl = lane & 15;
    int r4 = (lane >> 4) * 4;
#pragma unroll
    for (int fm = 0; fm < 4; ++fm)
#pragma unroll
        for (int fn = 0; fn < 4; ++fn)
#pragma unroll
            for (int r = 0; r < 4; ++r) {
                int row = m0 + wm + fm * 16 + r4 + r;
                int col = n0 + wn + fn * 16 + cl;
                atomicAdd(&hacc[row * NHID + col], acc[fm][fn][r]);
            }
}

// h = bf16(relu(hacc + b1))
__global__ __launch_bounds__(256) void bias_relu_h_kernel(
        const float* __restrict__ hacc, const float* __restrict__ b1,
        unsigned short* __restrict__ h) {
    int idx = blockIdx.x * 256 + threadIdx.x;   // 262144 total, 4 elems each
    f32x4 v = ((const f32x4*)hacc)[idx];
    int col = (idx & 127) << 2;
    f32x4 bb = *(const f32x4*)(b1 + col);
    short4v o;
#pragma unroll
    for (int e = 0; e < 4; ++e) {
        float x = v[e] + bb[e];
        x = fmaxf(x, 0.f);
        o[e] = (short)f2bf(x);
    }
    ((short4v*)h)[idx] = o;
}

// ---------------------------------------------------------------------------
// GEMM2: out = relu(h @ W2 + b2).  M=2048,N=512,K=512.  grid 16x4.
// ---------------------------------------------------------------------------
__global__ __launch_bounds__(256) void gemm2_kernel(
        const unsigned short* __restrict__ h, const unsigned short* __restrict__ W2t,
        const float* __restrict__ b2, float* __restrict__ out) {
    __shared__ unsigned short A_s[128 * 64];
    __shared__ unsigned short B_s[128 * 64];
    int m0 = (blockIdx.x >> 2) * 128;
    int n0 = (blockIdx.x & 3) * 128;
    int lane = threadIdx.x & 63;
    int wv = threadIdx.x >> 6;
    int wm = (wv >> 1) * 64;
    int wn = (wv & 1) * 64;

    f32x4 acc[4][4];
#pragma unroll
    for (int a = 0; a < 4; ++a)
#pragma unroll
        for (int b = 0; b < 4; ++b) acc[a][b] = (f32x4){0.f, 0.f, 0.f, 0.f};

    for (int st = 0; st < 8; ++st) {
        int kbase = st * 64;
        __syncthreads();
        stage_tile128(h,   m0, kbase, NHID, A_s);
        stage_tile128(W2t, n0, kbase, NHID, B_s);
        __syncthreads();
#pragma unroll
        for (int kk = 0; kk < 2; ++kk) {
            short8 aF[4], bF[4];
#pragma unroll
            for (int fm = 0; fm < 4; ++fm) aF[fm] = read_frag(A_s, wm + fm * 16, kk * 32, lane);
#pragma unroll
            for (int fn = 0; fn < 4; ++fn) bF[fn] = read_frag(B_s, wn + fn * 16, kk * 32, lane);
#pragma unroll
            for (int fm = 0; fm < 4; ++fm)
#pragma unroll
                for (int fn = 0; fn < 4; ++fn)
                    acc[fm][fn] = __builtin_amdgcn_mfma_f32_16x16x32_bf16(
                        aF[fm], bF[fn], acc[fm][fn], 0, 0, 0);
        }
    }
    int cl = lane & 15;
    int r4 = (lane >> 4) * 4;
#pragma unroll
    for (int fm = 0; fm < 4; ++fm)
#pragma unroll
        for (int fn = 0; fn < 4; ++fn)
#pragma unroll
            for (int r = 0; r < 4; ++r) {
                int row = m0 + wm + fm * 16 + r4 + r;
                int col = n0 + wn + fn * 16 + cl;
                float x = acc[fm][fn][r] + b2[col];
                out[row * NHID + col] = fmaxf(x, 0.f);
            }
}

extern "C" void kernel_launch(void* const* d_in, const int* in_sizes, int n_in,
                              void* d_out, int out_size, void* d_ws, size_t ws_size,
                              hipStream_t stream) {
    const float* inp1 = (const float*)d_in[0];
    const float* inp2 = (const float*)d_in[1];
    const float* W1   = (const float*)d_in[2];
    const float* b1   = (const float*)d_in[3];
    const float* W2   = (const float*)d_in[4];
    const float* b2   = (const float*)d_in[5];
    float* out = (float*)d_out;

    // workspace layout (~72.5 MB)
    size_t off = 0;
    auto alloc = [&](size_t bytes) {
        void* p = (char*)d_ws + off;
        off += (bytes + 255) & ~(size_t)255;
        return p;
    };
    unsigned short* W1t   = (unsigned short*)alloc((size_t)NHID * KPAD * 2);
    unsigned short* W2t   = (unsigned short*)alloc((size_t)NHID * NHID * 2);
    unsigned short* h     = (unsigned short*)alloc((size_t)BATCH * NHID * 2);
    unsigned short* a_tab = (unsigned short*)alloc((size_t)BATCH * AW * 2);
    unsigned short* c_tab = (unsigned short*)alloc((size_t)BATCH * CW * 2);
    (void)ws_size; (void)in_sizes; (void)n_in; (void)out_size;

    // d_out doubles as the f32 split-K accumulator for h_pre
    hipMemsetAsync(d_out, 0, (size_t)BATCH * NHID * 4, stream);

    prep_kernel<<<8264 + 64 + 64, 256, 0, stream>>>(inp1, inp2, W1, W2,
                                                    W1t, W2t, a_tab, c_tab);

    gemm1_kernel<<<64 * SPLITS, 256, 0, stream>>>(a_tab, c_tab, W1t, (float*)d_out);
    bias_relu_h_kernel<<<(BATCH * NHID / 4) / 256, 256, 0, stream>>>((const float*)d_out, b1, h);
    gemm2_kernel<<<64, 256, 0, stream>>>(h, W2t, b2, out);
}